// Round 17
// baseline (90.074 us; speedup 1.0000x reference)
//
#include <hip/hip_runtime.h>
#include <stdint.h>

// IDXST(4096x4096): y[r][k] = sum_n x[r][n] sin(pi*n*(2k+1)/8192).
// R20: R19 (tri-buffered counted-vmcnt quad-closed GEMM, 76.5us) with the
// B MATRICES GENERATED IN-KERNEL: Bo/Bp/Bq are pure functions of (row,k);
// each thread computes the exact 16B it previously gloaded (strip row ru*,
// chunk st_c, offset kn) via the SAME phase math as prep -> bit-identical
// values. 16(U)/8(PQ) __sinf + pack + ds_write_b128 per tile, placed after
// the MFMA cluster (VALU overlaps other waves' MFMA, m114; ~320cyc/SIMD ≪
// MFMA 620). prep loses its B section (108->96MB HBM, ~-2us); gemm loses
// 12MB of fetch + 2 vm-issues/tile. Ledger simplifies: EVERY tile issues
// exactly 4 A-gloads -> uniform W_VM4; lgkmcnt(0) before each tile-end
// barrier seals the ds_writes (tile's ds_reads already consumed by MFMA
// waits). Buffer rotation, A staging, epilogue fold identical to R19.
// ws (32 MB): xo 16 | xee 8 | xeo 8. prep = x-split only.

#define NN 4096

typedef __attribute__((ext_vector_type(8))) short short8;
typedef __attribute__((ext_vector_type(4))) float f32x4;

__device__ __forceinline__ unsigned short f2bf(float f) {
  unsigned int u = __float_as_uint(f);
  u += 0x7fffu + ((u >> 16) & 1u);
  return (unsigned short)(u >> 16);
}

__device__ __forceinline__ void async_load16(const void* g, void* lds) {
  __builtin_amdgcn_global_load_lds(
      (const __attribute__((address_space(1))) unsigned int*)g,
      (__attribute__((address_space(3))) unsigned int*)lds, 16, 0, 0);
}

#define NXS (NN * NN / 8)        // 2M x-split threads (8 floats each)

// prep: xo[r][m]=x[r][2m+1]; xee[r][t]=x[r][4t]; xeo[r][t]=x[r][4t+2].
__global__ void prep_kernel(const float* __restrict__ x,
                            unsigned short* __restrict__ xo,
                            unsigned short* __restrict__ xee,
                            unsigned short* __restrict__ xeo) {
  int gi = blockIdx.x * blockDim.x + threadIdx.x;
  int g = gi & 511;            // 8-float group in row
  int r = gi >> 9;
  const float4* src = (const float4*)(x + (size_t)r * NN + g * 8);
  float4 v0 = src[0], v1 = src[1];    // n = 8g+0..3, 8g+4..7
  ushort4 ov;                          // odd n -> m = 4g..4g+3
  ov.x = f2bf(v0.y); ov.y = f2bf(v0.w); ov.z = f2bf(v1.y); ov.w = f2bf(v1.w);
  *(ushort4*)&xo[(size_t)r * 2048 + g * 4] = ov;
  unsigned int ee = ((unsigned)f2bf(v1.x) << 16) | f2bf(v0.x);  // t=2g,2g+1
  *(unsigned int*)&xee[(size_t)r * 1024 + g * 2] = ee;
  unsigned int eo = ((unsigned)f2bf(v1.z) << 16) | f2bf(v0.z);
  *(unsigned int*)&xeo[(size_t)r * 1024 + g * 2] = eo;
}

// ---- LDS layout (ushort indices), 144 KiB -------------------------------
// A bufs: AB0=0, AB1=16384, AB2=32768 (32KB each: two 16KB halves).
// B bufs: BB0=49152, BB1=57344, BB2=65536 (16KB each; U uses both 8KB
// chunks, P/Q use the first 8KB).
#define AB0 0
#define AB1 16384
#define AB2 32768
#define BB0 49152
#define BB1 57344
#define BB2 65536

#define PH_BAR  __builtin_amdgcn_s_barrier()
#define W_LGKM0 asm volatile("s_waitcnt lgkmcnt(0)" ::: "memory")
#define W_VM4   asm volatile("s_waitcnt vmcnt(4)" ::: "memory")
#define W_VM0   asm volatile("s_waitcnt vmcnt(0)" ::: "memory")
#define PRIO1   __builtin_amdgcn_s_setprio(1)
#define PRIO0   __builtin_amdgcn_s_setprio(0)

// Stage a 128-row x 64-k A half-tile (16KB, 2 loads/thread). Linear LDS dest;
// source chunk pre-swizzled by the chunk^(row&7) involution the reads apply.
#define STAGEA_G(Abase, Kc, prow0, koff, off) do {                              \
    const unsigned short* _s =                                                  \
        (Abase) + (size_t)((prow0) + st_r) * (Kc) + (koff) + st_c;              \
    async_load16(_s, &lds[(off) + tid * 8]);                                    \
    async_load16(_s + (size_t)64 * (Kc), &lds[(off) + 4096 + tid * 8]);         \
  } while (0)

// Generate U B-chunk (both 8KB halves: rows ru0 and ru1) for k-cols
// [kn+st_c, +8) into B-buf bn. Same phase math as old prep -> identical bits.
#define GENB_U(bn, kn) do {                                                     \
    short8 _b0, _b1;                                                            \
    _Pragma("unroll") for (int _e = 0; _e < 8; ++_e) {                          \
      unsigned int _m = 2u * (unsigned)((kn) + st_c + _e) + 1u;                 \
      unsigned int _p0 = (_m * twu0) & 16383u;                                  \
      unsigned int _p1 = (_m * twu1) & 16383u;                                  \
      _b0[_e] = (short)f2bf(__sinf((float)_p0 * 3.83495197e-4f));               \
      _b1[_e] = (short)f2bf(__sinf((float)_p1 * 3.83495197e-4f));               \
    }                                                                           \
    *(short8*)&lds[(bn) + tid * 8] = _b0;                                       \
    *(short8*)&lds[(bn) + 4096 + tid * 8] = _b1;                                \
  } while (0)

// Generate P B-chunk (8KB, row rpq) for k-cols [kn+st_c,+8) into B-buf bn.
#define GENB_P(bn, kn) do {                                                     \
    short8 _b;                                                                  \
    _Pragma("unroll") for (int _e = 0; _e < 8; ++_e) {                          \
      unsigned int _p = ((unsigned)((kn) + st_c + _e) * twpq) & 4095u;          \
      _b[_e] = (short)f2bf(__sinf((float)_p * 1.53398079e-3f));                 \
    }                                                                           \
    *(short8*)&lds[(bn) + tid * 8] = _b;                                        \
  } while (0)

// Generate Q B-chunk (8KB, row rpq).
#define GENB_Q(bn, kn) do {                                                     \
    short8 _b;                                                                  \
    _Pragma("unroll") for (int _e = 0; _e < 8; ++_e) {                          \
      unsigned int _p = ((2u * (unsigned)((kn) + st_c + _e) + 1u) * twpq)       \
                        & 8191u;                                                \
      _b[_e] = (short)f2bf(__sinf((float)_p * 7.66990394e-4f));                 \
    }                                                                           \
    *(short8*)&lds[(bn) + tid * 8] = _b;                                        \
  } while (0)

// A-frags for row-half mh from A-buf base ab: 4 ds_read_b128.
#define LOADA3(ab, mh) do {                                                     \
    const int _ab = (ab) + wm * 4096 + (mh) * 2048 + lr * 64;                   \
    _Pragma("unroll") for (int _i = 0; _i < 2; ++_i) {                          \
      av[(mh) * 2 + _i][0] = *(const short8*)&lds[_ab + _i * 1024 + cA0];       \
      av[(mh) * 2 + _i][1] = *(const short8*)&lds[_ab + _i * 1024 + cA1];       \
    }                                                                           \
  } while (0)

// U B-frags for col-half nh from B-buf base bb: 4 ds_read_b128.
#define LOADBU3(SET, bb, nh) do {                                               \
    const int _bb = (bb) + wn * 4096 + (nh) * 2048 + lr * 64;                   \
    _Pragma("unroll") for (int _j = 0; _j < 2; ++_j) {                          \
      SET[_j][0] = *(const short8*)&lds[_bb + _j * 1024 + cA0];                 \
      SET[_j][1] = *(const short8*)&lds[_bb + _j * 1024 + cA1];                 \
    }                                                                           \
  } while (0)

// PQ B-frags from B-buf base bb (wave's 32 of 64 cols): 4 ds_read_b128.
#define LOADBP3(SET, bb) do {                                                   \
    const int _bb = (bb) + wn * 2048 + lr * 64;                                 \
    _Pragma("unroll") for (int _j = 0; _j < 2; ++_j) {                          \
      SET[_j][0] = *(const short8*)&lds[_bb + _j * 1024 + cA0];                 \
      SET[_j][1] = *(const short8*)&lds[_bb + _j * 1024 + cA1];                 \
    }                                                                           \
  } while (0)

// U quadrant (32x32) x K=64: 8 MFMA into uacc.
#define MMAQ_U(BS, mh, nh) do {                                                 \
    _Pragma("unroll") for (int _k = 0; _k < 2; ++_k)                            \
    _Pragma("unroll") for (int _i = 0; _i < 2; ++_i)                            \
    _Pragma("unroll") for (int _j = 0; _j < 2; ++_j)                            \
      uacc[(mh) * 2 + _i][(nh) * 2 + _j] =                                      \
          __builtin_amdgcn_mfma_f32_16x16x32_bf16(                              \
              av[(mh) * 2 + _i][_k], BS[_j][_k],                                \
              uacc[(mh) * 2 + _i][(nh) * 2 + _j], 0, 0, 0);                     \
  } while (0)

// P/Q half (32 rows x 32 cols) x K=64: 8 MFMA into ACC.
#define MMAQ_PQ(ACC, BS, mh) do {                                               \
    _Pragma("unroll") for (int _k = 0; _k < 2; ++_k)                            \
    _Pragma("unroll") for (int _i = 0; _i < 2; ++_i)                            \
    _Pragma("unroll") for (int _j = 0; _j < 2; ++_j)                            \
      ACC[(mh) * 2 + _i][_j] =                                                  \
          __builtin_amdgcn_mfma_f32_16x16x32_bf16(                              \
              av[(mh) * 2 + _i][_k], BS[_j][_k],                                \
              ACC[(mh) * 2 + _i][_j], 0, 0, 0);                                 \
  } while (0)

// Per-tile composites --------------------------------------------------------
#define U_CORE(ab, bb)                                                          \
    LOADA3(ab, 0); LOADA3(ab, 1);                                               \
    LOADBU3(bv0, bb, 0); LOADBU3(bv1, bb, 1)

#define U_MMA                                                                   \
    PRIO1; MMAQ_U(bv0, 0, 0); MMAQ_U(bv1, 0, 1);                                \
    MMAQ_U(bv1, 1, 1); MMAQ_U(bv0, 1, 0); PRIO0

#define STGA_U(an, kn)                                                          \
    STAGEA_G(xo, 2048, row0, kn, an);                                           \
    STAGEA_G(xo, 2048, row0 + 128, kn, (an) + 8192)

#define STGA_P(an, kn)                                                          \
    STAGEA_G(xee, 1024, row0, kn, an);                                          \
    STAGEA_G(xee, 1024, row0 + 128, kn, (an) + 8192)

#define STGA_Q(an, kn)                                                          \
    STAGEA_G(xeo, 1024, row0, kn, an);                                          \
    STAGEA_G(xeo, 1024, row0 + 128, kn, (an) + 8192)

#define PQ_CORE(ab, bb)                                                         \
    LOADA3(ab, 0); LOADA3(ab, 1); LOADBP3(bvp, bb)

#define PQ_MMA(ACC)                                                             \
    PRIO1; MMAQ_PQ(ACC, bvp, 0); MMAQ_PQ(ACC, bvp, 1); PRIO0

#define TILE_END  W_LGKM0; W_VM4; PH_BAR

__global__ __launch_bounds__(512) void gemm3_kernel(
    const unsigned short* __restrict__ xo,
    const unsigned short* __restrict__ xee,
    const unsigned short* __restrict__ xeo,
    float* __restrict__ out) {
  __shared__ __align__(16) unsigned short lds[73728];   // 144 KiB

  const int bx = blockIdx.x;           // 256 identical blocks
  const int row0 = (bx & 15) * 256;
  const int c0 = (bx >> 4) * 32;       // quad-group base k'

  const int tid = threadIdx.x;
  const int lane = tid & 63;
  const int wave = tid >> 6;
  const int wm = wave >> 1;            // 0..3 : 64-row strip
  const int wn = wave & 1;             // 0..1 : col-half (strip pair)
  const int lr = lane & 15, kq = lane >> 4;
  const int st_r = tid >> 3;                         // staging row 0..63
  const int st_c = ((tid & 7) ^ (st_r & 7)) * 8;     // pre-swizzled src chunk
  const int cA0 = (kq ^ (lr & 7)) * 8;               // swizzled ds_read chunks
  const int cA1 = ((4 + kq) ^ (lr & 7)) * 8;

  // B strip rows (mirror strips in reversed order) and twiddle factors.
  const int ru0 = (st_r < 32) ? (c0 + st_r) : (2047 - c0 - (st_r - 32));
  const int ru1 = (st_r < 32) ? (1023 - c0 - st_r) : (1024 + c0 + (st_r - 32));
  const int rpq = (st_r < 32) ? (c0 + st_r) : (1023 - c0 - (st_r - 32));
  const unsigned int twu0 = 2u * (unsigned)ru0 + 1u;
  const unsigned int twu1 = 2u * (unsigned)ru1 + 1u;
  const unsigned int twpq = 2u * (unsigned)rpq + 1u;

  f32x4 uacc[4][4], pacc[4][2], qacc[4][2];
#pragma unroll
  for (int i = 0; i < 4; ++i) {
#pragma unroll
    for (int j = 0; j < 4; ++j) uacc[i][j] = (f32x4){0.f, 0.f, 0.f, 0.f};
#pragma unroll
    for (int j = 0; j < 2; ++j) {
      pacc[i][j] = (f32x4){0.f, 0.f, 0.f, 0.f};
      qacc[i][j] = (f32x4){0.f, 0.f, 0.f, 0.f};
    }
  }
  short8 av[4][2], bv0[2][2], bv1[2][2], bvp[2][2];

  // Prologue: stage A for U0->buf0, U1->buf1 (8 gloads); gen B for U0,U1;
  // drain U0's A (leave U1's 4); seal B writes; barrier.
  STGA_U(AB0, 0);
  STGA_U(AB1, 64);
  GENB_U(BB0, 0);
  GENB_U(BB1, 64);
  TILE_END;

  // ================= U segment: 32 K-tiles, tri-buffered ===================
  // Tile g reads buf g%3; stages/gens tile g+2 into buf (g+2)%3.
  for (int it = 0; it < 10; ++it) {      // tiles 0..29
    const int kb = it * 192;
    U_CORE(AB0, BB0); STGA_U(AB2, kb + 128); U_MMA; GENB_U(BB2, kb + 128); TILE_END;
    U_CORE(AB1, BB1); STGA_U(AB0, kb + 192); U_MMA; GENB_U(BB0, kb + 192); TILE_END;
    U_CORE(AB2, BB2); STGA_U(AB1, kb + 256); U_MMA; GENB_U(BB1, kb + 256); TILE_END;
  }
  // U30 (buf0): stage/gen P0 -> buf2.  U31 (buf1): stage/gen P1 -> buf0.
  U_CORE(AB0, BB0); STGA_P(AB2, 0);  U_MMA; GENB_P(BB2, 0);  TILE_END;
  U_CORE(AB1, BB1); STGA_P(AB0, 64); U_MMA; GENB_P(BB0, 64); TILE_END;

  // ================= P segment: 16 K-tiles (P t in buf (t+2)%3) ============
  for (int it = 0; it < 4; ++it) {       // tiles 0..11
    const int kb = it * 192;
    PQ_CORE(AB2, BB2); STGA_P(AB1, kb + 128); PQ_MMA(pacc); GENB_P(BB1, kb + 128); TILE_END;
    PQ_CORE(AB0, BB0); STGA_P(AB2, kb + 192); PQ_MMA(pacc); GENB_P(BB2, kb + 192); TILE_END;
    PQ_CORE(AB1, BB1); STGA_P(AB0, kb + 256); PQ_MMA(pacc); GENB_P(BB0, kb + 256); TILE_END;
  }
  PQ_CORE(AB2, BB2); STGA_P(AB1, 896); PQ_MMA(pacc); GENB_P(BB1, 896); TILE_END;  // P12
  PQ_CORE(AB0, BB0); STGA_P(AB2, 960); PQ_MMA(pacc); GENB_P(BB2, 960); TILE_END;  // P13
  PQ_CORE(AB1, BB1); STGA_Q(AB0, 0);   PQ_MMA(pacc); GENB_Q(BB0, 0);   TILE_END;  // P14
  PQ_CORE(AB2, BB2); STGA_Q(AB1, 64);  PQ_MMA(pacc); GENB_Q(BB1, 64);  TILE_END;  // P15

  // ================= Q segment: 16 K-tiles (Q t in buf t%3) ================
  for (int it = 0; it < 4; ++it) {       // tiles 0..11
    const int kb = it * 192;
    PQ_CORE(AB0, BB0); STGA_Q(AB2, kb + 128); PQ_MMA(qacc); GENB_Q(BB2, kb + 128); TILE_END;
    PQ_CORE(AB1, BB1); STGA_Q(AB0, kb + 192); PQ_MMA(qacc); GENB_Q(BB0, kb + 192); TILE_END;
    PQ_CORE(AB2, BB2); STGA_Q(AB1, kb + 256); PQ_MMA(qacc); GENB_Q(BB1, kb + 256); TILE_END;
  }
  PQ_CORE(AB0, BB0); STGA_Q(AB2, 896); PQ_MMA(qacc); GENB_Q(BB2, 896); TILE_END;  // Q12
  PQ_CORE(AB1, BB1); STGA_Q(AB0, 960); PQ_MMA(qacc); GENB_Q(BB0, 960); TILE_END;  // Q13
  PQ_CORE(AB2, BB2); PQ_MMA(qacc); W_VM0; PH_BAR;                                 // Q14
  PQ_CORE(AB0, BB0); PQ_MMA(qacc);                                                // Q15

  // ===================== epilogue: full two-level fold =====================
  // wn=0: u1=u[k'], u4=u[2047-k'], p/q at k'.  wn=1: u1=u[1023-k'],
  // u4=u[1024+k'], p/q at 1023-k'.  k' = c0+cs, cs = j*16+lr.
#pragma unroll
  for (int i = 0; i < 4; ++i)
#pragma unroll
    for (int j = 0; j < 2; ++j)
#pragma unroll
      for (int rr = 0; rr < 4; ++rr) {
        const int r_out = row0 + wm * 64 + i * 16 + kq * 4 + rr;
        float* orow = out + (size_t)r_out * NN;
        const int cs = j * 16 + lr;
        const float u1 = uacc[i][j][rr];
        const float u4 = uacc[i][j + 2][rr];
        const float pa = pacc[i][j][rr];
        const float qa = qacc[i][j][rr];
        const float v1 = pa + qa;
        const float v2 = qa - pa;
        if (wn == 0) {
          orow[c0 + cs]        = v1 + u1;   // y[k']
          orow[4095 - c0 - cs] = u1 - v1;   // y[4095-k']
          orow[2047 - c0 - cs] = v2 + u4;   // y[2047-k']
          orow[2048 + c0 + cs] = u4 - v2;   // y[2048+k']
        } else {
          orow[1023 - c0 - cs] = v1 + u1;   // y[1023-k']
          orow[3072 + c0 + cs] = u1 - v1;   // y[3072+k']
          orow[1024 + c0 + cs] = v2 + u4;   // y[1024+k']
          orow[3071 - c0 - cs] = u4 - v2;   // y[3071-k']
        }
      }
}

extern "C" void kernel_launch(void* const* d_in, const int* in_sizes, int n_in,
                              void* d_out, int out_size, void* d_ws, size_t ws_size,
                              hipStream_t stream) {
  const float* x = (const float*)d_in[0];
  float* out = (float*)d_out;
  unsigned short* xo  = (unsigned short*)d_ws;            // 16 MB
  unsigned short* xee = xo + (size_t)NN * 2048;           // 8 MB
  unsigned short* xeo = xee + (size_t)NN * 1024;          // 8 MB -> 32 MB

  prep_kernel<<<NXS / 256, 256, 0, stream>>>(x, xo, xee, xeo);

  gemm3_kernel<<<256, 512, 0, stream>>>(xo, xee, xeo, out);
}

// Round 18
// 80.997 us; speedup vs baseline: 1.1121x; 1.1121x over previous
//
#include <hip/hip_runtime.h>
#include <stdint.h>

// IDXST(4096x4096): y[r][k] = sum_n x[r][n] sin(pi*n*(2k+1)/8192).
// R21: gemm = R19 EXACTLY (tri-buffered, counted-vmcnt, quad-closed grid,
// fold-in-epilogue; 58us, verified). R20 post-mortem: in-loop B generation
// put ~800cyc VALU on the per-tile critical path (budget ~340) -> reverted;
// B tables return to prep. NEW vs R19: prep stores vectorized (G13 on the
// write side). Old prep wrote 8B(xo)+4B+4B per thread; now each thread
// handles 32 floats (8x float4 reads = 128B/lane) and writes 2x16B (xo) +
// 16B (xee) + 16B (xeo). Same f2bf math/layout -> bit-identical buffers.
// prep: ~17 -> ~15.5-16.5us (HBM floor 15.2us for 96MB + 12MB B tables).
// ws (44 MB): xo 16 | xee 8 | xeo 8 | Bo 8 | Bp 2 | Bq 2.

#define NN 4096

typedef __attribute__((ext_vector_type(8))) short short8;
typedef __attribute__((ext_vector_type(4))) float f32x4;

__device__ __forceinline__ unsigned short f2bf(float f) {
  unsigned int u = __float_as_uint(f);
  u += 0x7fffu + ((u >> 16) & 1u);
  return (unsigned short)(u >> 16);
}

__device__ __forceinline__ void async_load16(const void* g, void* lds) {
  __builtin_amdgcn_global_load_lds(
      (const __attribute__((address_space(1))) unsigned int*)g,
      (__attribute__((address_space(3))) unsigned int*)lds, 16, 0, 0);
}

#define NXS (NN * NN / 32)       // 512K x-split threads (32 floats each)
#define NBO (2048 * 2048 / 4)    // 1M Bo threads
#define NBP (1024 * 1024 / 4)    // 256K Bp threads (Bq same)

// prep part 1: x-split, wide. Thread owns x[r][32c..32c+31]:
// xo[r][16c..16c+15] = odd samples (2x short8); xee/xeo 8 each (short8).
__global__ void prep_x_kernel(const float* __restrict__ x,
                              unsigned short* __restrict__ xo,
                              unsigned short* __restrict__ xee,
                              unsigned short* __restrict__ xeo) {
  int gi = blockIdx.x * blockDim.x + threadIdx.x;
  int c = gi & 127;            // 32-float group in row
  int r = gi >> 7;
  const float4* src = (const float4*)(x + (size_t)r * NN + c * 32);
  float4 f[8];
#pragma unroll
  for (int i = 0; i < 8; ++i) f[i] = src[i];
  short8 o0, o1, ee, eo;
#pragma unroll
  for (int i = 0; i < 4; ++i) {
    o0[2 * i]     = (short)f2bf(f[i].y);
    o0[2 * i + 1] = (short)f2bf(f[i].w);
    o1[2 * i]     = (short)f2bf(f[i + 4].y);
    o1[2 * i + 1] = (short)f2bf(f[i + 4].w);
  }
#pragma unroll
  for (int i = 0; i < 8; ++i) {
    ee[i] = (short)f2bf(f[i].x);
    eo[i] = (short)f2bf(f[i].z);
  }
  *(short8*)&xo[(size_t)r * 2048 + c * 16] = o0;
  *(short8*)&xo[(size_t)r * 2048 + c * 16 + 8] = o1;
  *(short8*)&xee[(size_t)r * 1024 + c * 8] = ee;
  *(short8*)&xeo[(size_t)r * 1024 + c * 8] = eo;
}

// prep part 2: B tables (unchanged math from the verified prep).
// Bo[c][m]=sin(pi(2m+1)(2c+1)/8192); Bp[c][t]=sin(pi*t*(2c+1)/2048);
// Bq[c][t]=sin(pi(2t+1)(2c+1)/4096)
__global__ void prep_b_kernel(unsigned short* __restrict__ Bo,
                              unsigned short* __restrict__ Bp,
                              unsigned short* __restrict__ Bq) {
  int gi = blockIdx.x * blockDim.x + threadIdx.x;
  if (gi < NBO) {
    int i = gi;
    int m0 = (i & 511) * 4;
    int c = i >> 9;
    unsigned int tw = 2u * (unsigned)c + 1u;
    const float sc = 3.14159265358979323846f / 8192.0f;
    ushort4 o; unsigned int ph;
    ph = ((unsigned)(2 * (m0 + 0) + 1) * tw) & 16383u; o.x = f2bf(__sinf((float)ph * sc));
    ph = ((unsigned)(2 * (m0 + 1) + 1) * tw) & 16383u; o.y = f2bf(__sinf((float)ph * sc));
    ph = ((unsigned)(2 * (m0 + 2) + 1) * tw) & 16383u; o.z = f2bf(__sinf((float)ph * sc));
    ph = ((unsigned)(2 * (m0 + 3) + 1) * tw) & 16383u; o.w = f2bf(__sinf((float)ph * sc));
    *(ushort4*)&Bo[(size_t)c * 2048 + m0] = o;
  } else if (gi < NBO + NBP) {
    int i = gi - NBO;
    int t0 = (i & 255) * 4;
    int c = i >> 8;
    unsigned int tw = 2u * (unsigned)c + 1u;
    const float sc = 3.14159265358979323846f / 2048.0f;
    ushort4 o; unsigned int ph;
    ph = ((unsigned)(t0 + 0) * tw) & 4095u; o.x = f2bf(__sinf((float)ph * sc));
    ph = ((unsigned)(t0 + 1) * tw) & 4095u; o.y = f2bf(__sinf((float)ph * sc));
    ph = ((unsigned)(t0 + 2) * tw) & 4095u; o.z = f2bf(__sinf((float)ph * sc));
    ph = ((unsigned)(t0 + 3) * tw) & 4095u; o.w = f2bf(__sinf((float)ph * sc));
    *(ushort4*)&Bp[(size_t)c * 1024 + t0] = o;
  } else {
    int i = gi - NBO - NBP;
    int t0 = (i & 255) * 4;
    int c = i >> 8;
    unsigned int tw = 2u * (unsigned)c + 1u;
    const float sc = 3.14159265358979323846f / 4096.0f;
    ushort4 o; unsigned int ph;
    ph = ((unsigned)(2 * (t0 + 0) + 1) * tw) & 8191u; o.x = f2bf(__sinf((float)ph * sc));
    ph = ((unsigned)(2 * (t0 + 1) + 1) * tw) & 8191u; o.y = f2bf(__sinf((float)ph * sc));
    ph = ((unsigned)(2 * (t0 + 2) + 1) * tw) & 8191u; o.z = f2bf(__sinf((float)ph * sc));
    ph = ((unsigned)(2 * (t0 + 3) + 1) * tw) & 8191u; o.w = f2bf(__sinf((float)ph * sc));
    *(ushort4*)&Bq[(size_t)c * 1024 + t0] = o;
  }
}

// ---- LDS layout (ushort indices), 144 KiB -------------------------------
// A bufs: AB0=0, AB1=16384, AB2=32768 (32KB each: two 16KB halves).
// B bufs: BB0=49152, BB1=57344, BB2=65536 (16KB each; U uses both 8KB
// chunks, P/Q use the first 8KB).
#define AB0 0
#define AB1 16384
#define AB2 32768
#define BB0 49152
#define BB1 57344
#define BB2 65536

#define PH_BAR  __builtin_amdgcn_s_barrier()
#define W_VM6   asm volatile("s_waitcnt vmcnt(6)" ::: "memory")
#define W_VM5   asm volatile("s_waitcnt vmcnt(5)" ::: "memory")
#define W_VM0   asm volatile("s_waitcnt vmcnt(0)" ::: "memory")
#define PRIO1   __builtin_amdgcn_s_setprio(1)
#define PRIO0   __builtin_amdgcn_s_setprio(0)

// Stage a 128-row x 64-k A half-tile (16KB, 2 loads/thread). Linear LDS dest;
// source chunk pre-swizzled by the chunk^(row&7) involution the reads apply.
#define STAGEA_G(Abase, Kc, prow0, koff, off) do {                              \
    const unsigned short* _s =                                                  \
        (Abase) + (size_t)((prow0) + st_r) * (Kc) + (koff) + st_c;              \
    async_load16(_s, &lds[(off) + tid * 8]);                                    \
    async_load16(_s + (size_t)64 * (Kc), &lds[(off) + 4096 + tid * 8]);         \
  } while (0)

// Stage one 64-row B chunk (8KB, 1 load/thread) from a per-thread strip ptr.
#define STAGEB_P(srcp, koff, off)                                               \
    async_load16((srcp) + (koff), &lds[(off) + tid * 8])

// A-frags for row-half mh from A-buf base ab: 4 ds_read_b128.
#define LOADA3(ab, mh) do {                                                     \
    const int _ab = (ab) + wm * 4096 + (mh) * 2048 + lr * 64;                   \
    _Pragma("unroll") for (int _i = 0; _i < 2; ++_i) {                          \
      av[(mh) * 2 + _i][0] = *(const short8*)&lds[_ab + _i * 1024 + cA0];       \
      av[(mh) * 2 + _i][1] = *(const short8*)&lds[_ab + _i * 1024 + cA1];       \
    }                                                                           \
  } while (0)

// U B-frags for col-half nh from B-buf base bb: 4 ds_read_b128.
#define LOADBU3(SET, bb, nh) do {                                               \
    const int _bb = (bb) + wn * 4096 + (nh) * 2048 + lr * 64;                   \
    _Pragma("unroll") for (int _j = 0; _j < 2; ++_j) {                          \
      SET[_j][0] = *(const short8*)&lds[_bb + _j * 1024 + cA0];                 \
      SET[_j][1] = *(const short8*)&lds[_bb + _j * 1024 + cA1];                 \
    }                                                                           \
  } while (0)

// PQ B-frags from B-buf base bb (wave's 32 of 64 cols): 4 ds_read_b128.
#define LOADBP3(SET, bb) do {                                                   \
    const int _bb = (bb) + wn * 2048 + lr * 64;                                 \
    _Pragma("unroll") for (int _j = 0; _j < 2; ++_j) {                          \
      SET[_j][0] = *(const short8*)&lds[_bb + _j * 1024 + cA0];                 \
      SET[_j][1] = *(const short8*)&lds[_bb + _j * 1024 + cA1];                 \
    }                                                                           \
  } while (0)

// U quadrant (32x32) x K=64: 8 MFMA into uacc.
#define MMAQ_U(BS, mh, nh) do {                                                 \
    _Pragma("unroll") for (int _k = 0; _k < 2; ++_k)                            \
    _Pragma("unroll") for (int _i = 0; _i < 2; ++_i)                            \
    _Pragma("unroll") for (int _j = 0; _j < 2; ++_j)                            \
      uacc[(mh) * 2 + _i][(nh) * 2 + _j] =                                      \
          __builtin_amdgcn_mfma_f32_16x16x32_bf16(                              \
              av[(mh) * 2 + _i][_k], BS[_j][_k],                                \
              uacc[(mh) * 2 + _i][(nh) * 2 + _j], 0, 0, 0);                     \
  } while (0)

// P/Q half (32 rows x 32 cols) x K=64: 8 MFMA into ACC.
#define MMAQ_PQ(ACC, BS, mh) do {                                               \
    _Pragma("unroll") for (int _k = 0; _k < 2; ++_k)                            \
    _Pragma("unroll") for (int _i = 0; _i < 2; ++_i)                            \
    _Pragma("unroll") for (int _j = 0; _j < 2; ++_j)                            \
      ACC[(mh) * 2 + _i][_j] =                                                  \
          __builtin_amdgcn_mfma_f32_16x16x32_bf16(                              \
              av[(mh) * 2 + _i][_k], BS[_j][_k],                                \
              ACC[(mh) * 2 + _i][_j], 0, 0, 0);                                 \
  } while (0)

// Per-tile composites --------------------------------------------------------
#define U_CORE(ab, bb)                                                          \
    LOADA3(ab, 0); LOADA3(ab, 1);                                               \
    LOADBU3(bv0, bb, 0); LOADBU3(bv1, bb, 1)

#define U_MMA                                                                   \
    PRIO1; MMAQ_U(bv0, 0, 0); MMAQ_U(bv1, 0, 1);                                \
    MMAQ_U(bv1, 1, 1); MMAQ_U(bv0, 1, 0); PRIO0

#define STG_U(an, bn, kn)                                                       \
    STAGEA_G(xo, 2048, row0, kn, an);                                           \
    STAGEA_G(xo, 2048, row0 + 128, kn, (an) + 8192);                            \
    STAGEB_P(sBo0, kn, bn);                                                     \
    STAGEB_P(sBo1, kn, (bn) + 4096)

#define STG_P(an, bn, kn)                                                       \
    STAGEA_G(xee, 1024, row0, kn, an);                                          \
    STAGEA_G(xee, 1024, row0 + 128, kn, (an) + 8192);                           \
    STAGEB_P(sBp, kn, bn)

#define STG_Q(an, bn, kn)                                                       \
    STAGEA_G(xeo, 1024, row0, kn, an);                                          \
    STAGEA_G(xeo, 1024, row0 + 128, kn, (an) + 8192);                           \
    STAGEB_P(sBq, kn, bn)

#define PQ_CORE(ab, bb)                                                         \
    LOADA3(ab, 0); LOADA3(ab, 1); LOADBP3(bvp, bb)

#define PQ_MMA(ACC)                                                             \
    PRIO1; MMAQ_PQ(ACC, bvp, 0); MMAQ_PQ(ACC, bvp, 1); PRIO0

__global__ __launch_bounds__(512) void gemm3_kernel(
    const unsigned short* __restrict__ xo,
    const unsigned short* __restrict__ xee,
    const unsigned short* __restrict__ xeo,
    const unsigned short* __restrict__ Bo,
    const unsigned short* __restrict__ Bp,
    const unsigned short* __restrict__ Bq,
    float* __restrict__ out) {
  __shared__ __align__(16) unsigned short lds[73728];   // 144 KiB

  const int bx = blockIdx.x;           // 256 identical blocks
  const int row0 = (bx & 15) * 256;
  const int c0 = (bx >> 4) * 32;       // quad-group base k'

  const int tid = threadIdx.x;
  const int lane = tid & 63;
  const int wave = tid >> 6;
  const int wm = wave >> 1;            // 0..3 : 64-row strip
  const int wn = wave & 1;             // 0..1 : col-half (strip pair)
  const int lr = lane & 15, kq = lane >> 4;
  const int st_r = tid >> 3;                         // staging row 0..63
  const int st_c = ((tid & 7) ^ (st_r & 7)) * 8;     // pre-swizzled src chunk
  const int cA0 = (kq ^ (lr & 7)) * 8;               // swizzled ds_read chunks
  const int cA1 = ((4 + kq) ^ (lr & 7)) * 8;

  // Per-thread B staging row pointers (strip-gather; mirrors reversed).
  const int ru0 = (st_r < 32) ? (c0 + st_r) : (2047 - c0 - (st_r - 32));
  const int ru1 = (st_r < 32) ? (1023 - c0 - st_r) : (1024 + c0 + (st_r - 32));
  const int rpq = (st_r < 32) ? (c0 + st_r) : (1023 - c0 - (st_r - 32));
  const unsigned short* sBo0 = Bo + (size_t)ru0 * 2048 + st_c;
  const unsigned short* sBo1 = Bo + (size_t)ru1 * 2048 + st_c;
  const unsigned short* sBp  = Bp + (size_t)rpq * 1024 + st_c;
  const unsigned short* sBq  = Bq + (size_t)rpq * 1024 + st_c;

  f32x4 uacc[4][4], pacc[4][2], qacc[4][2];
#pragma unroll
  for (int i = 0; i < 4; ++i) {
#pragma unroll
    for (int j = 0; j < 4; ++j) uacc[i][j] = (f32x4){0.f, 0.f, 0.f, 0.f};
#pragma unroll
    for (int j = 0; j < 2; ++j) {
      pacc[i][j] = (f32x4){0.f, 0.f, 0.f, 0.f};
      qacc[i][j] = (f32x4){0.f, 0.f, 0.f, 0.f};
    }
  }
  short8 av[4][2], bv0[2][2], bv1[2][2], bvp[2][2];

  // Prologue: stage U0 -> buf0, U1 -> buf1 (12 loads); drain U0, keep U1.
  STG_U(AB0, BB0, 0);
  STG_U(AB1, BB1, 64);
  W_VM6; PH_BAR;

  // ================= U segment: 32 K-tiles, tri-buffered ===================
  for (int it = 0; it < 10; ++it) {      // tiles 0..29
    const int kb = it * 192;
    U_CORE(AB0, BB0); STG_U(AB2, BB2, kb + 128); U_MMA; W_VM6; PH_BAR;
    U_CORE(AB1, BB1); STG_U(AB0, BB0, kb + 192); U_MMA; W_VM6; PH_BAR;
    U_CORE(AB2, BB2); STG_U(AB1, BB1, kb + 256); U_MMA; W_VM6; PH_BAR;
  }
  // U30 (buf0): stage P0 -> buf2 (drain U31's 6, leave P0's 5)
  U_CORE(AB0, BB0); STG_P(AB2, BB2, 0); U_MMA; W_VM5; PH_BAR;
  // U31 (buf1): stage P1 -> buf0 (drain P0's 5, leave P1's 5)
  U_CORE(AB1, BB1); STG_P(AB0, BB0, 64); U_MMA; W_VM5; PH_BAR;

  // ================= P segment: 16 K-tiles (P t in buf (t+2)%3) ============
  for (int it = 0; it < 4; ++it) {       // tiles 0..11
    const int kb = it * 192;
    PQ_CORE(AB2, BB2); STG_P(AB1, BB1, kb + 128); PQ_MMA(pacc); W_VM5; PH_BAR;
    PQ_CORE(AB0, BB0); STG_P(AB2, BB2, kb + 192); PQ_MMA(pacc); W_VM5; PH_BAR;
    PQ_CORE(AB1, BB1); STG_P(AB0, BB0, kb + 256); PQ_MMA(pacc); W_VM5; PH_BAR;
  }
  PQ_CORE(AB2, BB2); STG_P(AB1, BB1, 896); PQ_MMA(pacc); W_VM5; PH_BAR;  // P12
  PQ_CORE(AB0, BB0); STG_P(AB2, BB2, 960); PQ_MMA(pacc); W_VM5; PH_BAR;  // P13
  PQ_CORE(AB1, BB1); STG_Q(AB0, BB0, 0);   PQ_MMA(pacc); W_VM5; PH_BAR;  // P14
  PQ_CORE(AB2, BB2); STG_Q(AB1, BB1, 64);  PQ_MMA(pacc); W_VM5; PH_BAR;  // P15

  // ================= Q segment: 16 K-tiles (Q t in buf t%3) ================
  for (int it = 0; it < 4; ++it) {       // tiles 0..11
    const int kb = it * 192;
    PQ_CORE(AB0, BB0); STG_Q(AB2, BB2, kb + 128); PQ_MMA(qacc); W_VM5; PH_BAR;
    PQ_CORE(AB1, BB1); STG_Q(AB0, BB0, kb + 192); PQ_MMA(qacc); W_VM5; PH_BAR;
    PQ_CORE(AB2, BB2); STG_Q(AB1, BB1, kb + 256); PQ_MMA(qacc); W_VM5; PH_BAR;
  }
  PQ_CORE(AB0, BB0); STG_Q(AB2, BB2, 896); PQ_MMA(qacc); W_VM5; PH_BAR;  // Q12
  PQ_CORE(AB1, BB1); STG_Q(AB0, BB0, 960); PQ_MMA(qacc); W_VM5; PH_BAR;  // Q13
  PQ_CORE(AB2, BB2); PQ_MMA(qacc); W_VM0; PH_BAR;                        // Q14
  PQ_CORE(AB0, BB0); PQ_MMA(qacc);                                       // Q15

  // ===================== epilogue: full two-level fold =====================
  // wn=0: u1=u[k'], u4=u[2047-k'], p/q at k'.  wn=1: u1=u[1023-k'],
  // u4=u[1024+k'], p/q at 1023-k'.  k' = c0+cs, cs = j*16+lr.
#pragma unroll
  for (int i = 0; i < 4; ++i)
#pragma unroll
    for (int j = 0; j < 2; ++j)
#pragma unroll
      for (int rr = 0; rr < 4; ++rr) {
        const int r_out = row0 + wm * 64 + i * 16 + kq * 4 + rr;
        float* orow = out + (size_t)r_out * NN;
        const int cs = j * 16 + lr;
        const float u1 = uacc[i][j][rr];
        const float u4 = uacc[i][j + 2][rr];
        const float pa = pacc[i][j][rr];
        const float qa = qacc[i][j][rr];
        const float v1 = pa + qa;
        const float v2 = qa - pa;
        if (wn == 0) {
          orow[c0 + cs]        = v1 + u1;   // y[k']
          orow[4095 - c0 - cs] = u1 - v1;   // y[4095-k']
          orow[2047 - c0 - cs] = v2 + u4;   // y[2047-k']
          orow[2048 + c0 + cs] = u4 - v2;   // y[2048+k']
        } else {
          orow[1023 - c0 - cs] = v1 + u1;   // y[1023-k']
          orow[3072 + c0 + cs] = u1 - v1;   // y[3072+k']
          orow[1024 + c0 + cs] = v2 + u4;   // y[1024+k']
          orow[3071 - c0 - cs] = u4 - v2;   // y[3071-k']
        }
      }
}

extern "C" void kernel_launch(void* const* d_in, const int* in_sizes, int n_in,
                              void* d_out, int out_size, void* d_ws, size_t ws_size,
                              hipStream_t stream) {
  const float* x = (const float*)d_in[0];
  float* out = (float*)d_out;
  unsigned short* xo  = (unsigned short*)d_ws;            // 16 MB
  unsigned short* xee = xo + (size_t)NN * 2048;           // 8 MB
  unsigned short* xeo = xee + (size_t)NN * 1024;          // 8 MB
  unsigned short* Bo  = xeo + (size_t)NN * 1024;          // 8 MB
  unsigned short* Bp  = Bo + (size_t)2048 * 2048;         // 2 MB
  unsigned short* Bq  = Bp + (size_t)1024 * 1024;         // 2 MB -> 44 MB total

  prep_x_kernel<<<NXS / 256, 256, 0, stream>>>(x, xo, xee, xeo);
  prep_b_kernel<<<(NBO + 2 * NBP) / 256, 256, 0, stream>>>(Bo, Bp, Bq);

  gemm3_kernel<<<256, 512, 0, stream>>>(xo, xee, xeo, Bo, Bp, Bq, out);
}

// Round 19
// 77.748 us; speedup vs baseline: 1.1585x; 1.0418x over previous
//
#include <hip/hip_runtime.h>
#include <stdint.h>

// IDXST(4096x4096): y[r][k] = sum_n x[r][n] sin(pi*n*(2k+1)/8192).
// R22: gemm = R19 EXACTLY (tri-buffered, counted-vmcnt, quad-closed grid,
// fold-in-epilogue; 58us, verified 3x). prep = SINGLE dispatch again (R21's
// two-kernel split serialized the HBM-bound x-part and the VALU-bound
// B-tables, costing 4.5us of lost overlap) but keeps R21's vectorized
// x-split: 32 floats/thread, stores 2x16B(xo)+16B(xee)+16B(xeo) (write-side
// G13). B-table sections unchanged (bit-identical to verified prep).
// Thread ranges: [0,512K) x-split | [512K, +1M) Bo | +256K Bp | +256K Bq.
// ws (44 MB): xo 16 | xee 8 | xeo 8 | Bo 8 | Bp 2 | Bq 2.

#define NN 4096

typedef __attribute__((ext_vector_type(8))) short short8;
typedef __attribute__((ext_vector_type(4))) float f32x4;

__device__ __forceinline__ unsigned short f2bf(float f) {
  unsigned int u = __float_as_uint(f);
  u += 0x7fffu + ((u >> 16) & 1u);
  return (unsigned short)(u >> 16);
}

__device__ __forceinline__ void async_load16(const void* g, void* lds) {
  __builtin_amdgcn_global_load_lds(
      (const __attribute__((address_space(1))) unsigned int*)g,
      (__attribute__((address_space(3))) unsigned int*)lds, 16, 0, 0);
}

#define NXS (NN * NN / 32)       // 512K x-split threads (32 floats each)
#define NBO (2048 * 2048 / 4)    // 1M Bo threads
#define NBP (1024 * 1024 / 4)    // 256K Bp threads (Bq same)

// prep (ONE dispatch): x-split (wide) + Bo + Bp + Bq.
__global__ void prep_kernel(const float* __restrict__ x,
                            unsigned short* __restrict__ xo,
                            unsigned short* __restrict__ xee,
                            unsigned short* __restrict__ xeo,
                            unsigned short* __restrict__ Bo,
                            unsigned short* __restrict__ Bp,
                            unsigned short* __restrict__ Bq) {
  int gi = blockIdx.x * blockDim.x + threadIdx.x;
  if (gi < NXS) {
    int c = gi & 127;            // 32-float group in row
    int r = gi >> 7;
    const float4* src = (const float4*)(x + (size_t)r * NN + c * 32);
    float4 f[8];
#pragma unroll
    for (int i = 0; i < 8; ++i) f[i] = src[i];
    short8 o0, o1, ee, eo;
#pragma unroll
    for (int i = 0; i < 4; ++i) {
      o0[2 * i]     = (short)f2bf(f[i].y);
      o0[2 * i + 1] = (short)f2bf(f[i].w);
      o1[2 * i]     = (short)f2bf(f[i + 4].y);
      o1[2 * i + 1] = (short)f2bf(f[i + 4].w);
    }
#pragma unroll
    for (int i = 0; i < 8; ++i) {
      ee[i] = (short)f2bf(f[i].x);
      eo[i] = (short)f2bf(f[i].z);
    }
    *(short8*)&xo[(size_t)r * 2048 + c * 16] = o0;
    *(short8*)&xo[(size_t)r * 2048 + c * 16 + 8] = o1;
    *(short8*)&xee[(size_t)r * 1024 + c * 8] = ee;
    *(short8*)&xeo[(size_t)r * 1024 + c * 8] = eo;
  } else if (gi < NXS + NBO) {
    int i = gi - NXS;
    int m0 = (i & 511) * 4;
    int c = i >> 9;
    unsigned int tw = 2u * (unsigned)c + 1u;
    const float sc = 3.14159265358979323846f / 8192.0f;
    ushort4 o; unsigned int ph;
    ph = ((unsigned)(2 * (m0 + 0) + 1) * tw) & 16383u; o.x = f2bf(__sinf((float)ph * sc));
    ph = ((unsigned)(2 * (m0 + 1) + 1) * tw) & 16383u; o.y = f2bf(__sinf((float)ph * sc));
    ph = ((unsigned)(2 * (m0 + 2) + 1) * tw) & 16383u; o.z = f2bf(__sinf((float)ph * sc));
    ph = ((unsigned)(2 * (m0 + 3) + 1) * tw) & 16383u; o.w = f2bf(__sinf((float)ph * sc));
    *(ushort4*)&Bo[(size_t)c * 2048 + m0] = o;
  } else if (gi < NXS + NBO + NBP) {
    int i = gi - NXS - NBO;
    int t0 = (i & 255) * 4;
    int c = i >> 8;
    unsigned int tw = 2u * (unsigned)c + 1u;
    const float sc = 3.14159265358979323846f / 2048.0f;
    ushort4 o; unsigned int ph;
    ph = ((unsigned)(t0 + 0) * tw) & 4095u; o.x = f2bf(__sinf((float)ph * sc));
    ph = ((unsigned)(t0 + 1) * tw) & 4095u; o.y = f2bf(__sinf((float)ph * sc));
    ph = ((unsigned)(t0 + 2) * tw) & 4095u; o.z = f2bf(__sinf((float)ph * sc));
    ph = ((unsigned)(t0 + 3) * tw) & 4095u; o.w = f2bf(__sinf((float)ph * sc));
    *(ushort4*)&Bp[(size_t)c * 1024 + t0] = o;
  } else {
    int i = gi - NXS - NBO - NBP;
    int t0 = (i & 255) * 4;
    int c = i >> 8;
    unsigned int tw = 2u * (unsigned)c + 1u;
    const float sc = 3.14159265358979323846f / 4096.0f;
    ushort4 o; unsigned int ph;
    ph = ((unsigned)(2 * (t0 + 0) + 1) * tw) & 8191u; o.x = f2bf(__sinf((float)ph * sc));
    ph = ((unsigned)(2 * (t0 + 1) + 1) * tw) & 8191u; o.y = f2bf(__sinf((float)ph * sc));
    ph = ((unsigned)(2 * (t0 + 2) + 1) * tw) & 8191u; o.z = f2bf(__sinf((float)ph * sc));
    ph = ((unsigned)(2 * (t0 + 3) + 1) * tw) & 8191u; o.w = f2bf(__sinf((float)ph * sc));
    *(ushort4*)&Bq[(size_t)c * 1024 + t0] = o;
  }
}

// ---- LDS layout (ushort indices), 144 KiB -------------------------------
// A bufs: AB0=0, AB1=16384, AB2=32768 (32KB each: two 16KB halves).
// B bufs: BB0=49152, BB1=57344, BB2=65536 (16KB each; U uses both 8KB
// chunks, P/Q use the first 8KB).
#define AB0 0
#define AB1 16384
#define AB2 32768
#define BB0 49152
#define BB1 57344
#define BB2 65536

#define PH_BAR  __builtin_amdgcn_s_barrier()
#define W_VM6   asm volatile("s_waitcnt vmcnt(6)" ::: "memory")
#define W_VM5   asm volatile("s_waitcnt vmcnt(5)" ::: "memory")
#define W_VM0   asm volatile("s_waitcnt vmcnt(0)" ::: "memory")
#define PRIO1   __builtin_amdgcn_s_setprio(1)
#define PRIO0   __builtin_amdgcn_s_setprio(0)

// Stage a 128-row x 64-k A half-tile (16KB, 2 loads/thread). Linear LDS dest;
// source chunk pre-swizzled by the chunk^(row&7) involution the reads apply.
#define STAGEA_G(Abase, Kc, prow0, koff, off) do {                              \
    const unsigned short* _s =                                                  \
        (Abase) + (size_t)((prow0) + st_r) * (Kc) + (koff) + st_c;              \
    async_load16(_s, &lds[(off) + tid * 8]);                                    \
    async_load16(_s + (size_t)64 * (Kc), &lds[(off) + 4096 + tid * 8]);         \
  } while (0)

// Stage one 64-row B chunk (8KB, 1 load/thread) from a per-thread strip ptr.
#define STAGEB_P(srcp, koff, off)                                               \
    async_load16((srcp) + (koff), &lds[(off) + tid * 8])

// A-frags for row-half mh from A-buf base ab: 4 ds_read_b128.
#define LOADA3(ab, mh) do {                                                     \
    const int _ab = (ab) + wm * 4096 + (mh) * 2048 + lr * 64;                   \
    _Pragma("unroll") for (int _i = 0; _i < 2; ++_i) {                          \
      av[(mh) * 2 + _i][0] = *(const short8*)&lds[_ab + _i * 1024 + cA0];       \
      av[(mh) * 2 + _i][1] = *(const short8*)&lds[_ab + _i * 1024 + cA1];       \
    }                                                                           \
  } while (0)

// U B-frags for col-half nh from B-buf base bb: 4 ds_read_b128.
#define LOADBU3(SET, bb, nh) do {                                               \
    const int _bb = (bb) + wn * 4096 + (nh) * 2048 + lr * 64;                   \
    _Pragma("unroll") for (int _j = 0; _j < 2; ++_j) {                          \
      SET[_j][0] = *(const short8*)&lds[_bb + _j * 1024 + cA0];                 \
      SET[_j][1] = *(const short8*)&lds[_bb + _j * 1024 + cA1];                 \
    }                                                                           \
  } while (0)

// PQ B-frags from B-buf base bb (wave's 32 of 64 cols): 4 ds_read_b128.
#define LOADBP3(SET, bb) do {                                                   \
    const int _bb = (bb) + wn * 2048 + lr * 64;                                 \
    _Pragma("unroll") for (int _j = 0; _j < 2; ++_j) {                          \
      SET[_j][0] = *(const short8*)&lds[_bb + _j * 1024 + cA0];                 \
      SET[_j][1] = *(const short8*)&lds[_bb + _j * 1024 + cA1];                 \
    }                                                                           \
  } while (0)

// U quadrant (32x32) x K=64: 8 MFMA into uacc.
#define MMAQ_U(BS, mh, nh) do {                                                 \
    _Pragma("unroll") for (int _k = 0; _k < 2; ++_k)                            \
    _Pragma("unroll") for (int _i = 0; _i < 2; ++_i)                            \
    _Pragma("unroll") for (int _j = 0; _j < 2; ++_j)                            \
      uacc[(mh) * 2 + _i][(nh) * 2 + _j] =                                      \
          __builtin_amdgcn_mfma_f32_16x16x32_bf16(                              \
              av[(mh) * 2 + _i][_k], BS[_j][_k],                                \
              uacc[(mh) * 2 + _i][(nh) * 2 + _j], 0, 0, 0);                     \
  } while (0)

// P/Q half (32 rows x 32 cols) x K=64: 8 MFMA into ACC.
#define MMAQ_PQ(ACC, BS, mh) do {                                               \
    _Pragma("unroll") for (int _k = 0; _k < 2; ++_k)                            \
    _Pragma("unroll") for (int _i = 0; _i < 2; ++_i)                            \
    _Pragma("unroll") for (int _j = 0; _j < 2; ++_j)                            \
      ACC[(mh) * 2 + _i][_j] =                                                  \
          __builtin_amdgcn_mfma_f32_16x16x32_bf16(                              \
              av[(mh) * 2 + _i][_k], BS[_j][_k],                                \
              ACC[(mh) * 2 + _i][_j], 0, 0, 0);                                 \
  } while (0)

// Per-tile composites --------------------------------------------------------
#define U_CORE(ab, bb)                                                          \
    LOADA3(ab, 0); LOADA3(ab, 1);                                               \
    LOADBU3(bv0, bb, 0); LOADBU3(bv1, bb, 1)

#define U_MMA                                                                   \
    PRIO1; MMAQ_U(bv0, 0, 0); MMAQ_U(bv1, 0, 1);                                \
    MMAQ_U(bv1, 1, 1); MMAQ_U(bv0, 1, 0); PRIO0

#define STG_U(an, bn, kn)                                                       \
    STAGEA_G(xo, 2048, row0, kn, an);                                           \
    STAGEA_G(xo, 2048, row0 + 128, kn, (an) + 8192);                            \
    STAGEB_P(sBo0, kn, bn);                                                     \
    STAGEB_P(sBo1, kn, (bn) + 4096)

#define STG_P(an, bn, kn)                                                       \
    STAGEA_G(xee, 1024, row0, kn, an);                                          \
    STAGEA_G(xee, 1024, row0 + 128, kn, (an) + 8192);                           \
    STAGEB_P(sBp, kn, bn)

#define STG_Q(an, bn, kn)                                                       \
    STAGEA_G(xeo, 1024, row0, kn, an);                                          \
    STAGEA_G(xeo, 1024, row0 + 128, kn, (an) + 8192);                           \
    STAGEB_P(sBq, kn, bn)

#define PQ_CORE(ab, bb)                                                         \
    LOADA3(ab, 0); LOADA3(ab, 1); LOADBP3(bvp, bb)

#define PQ_MMA(ACC)                                                             \
    PRIO1; MMAQ_PQ(ACC, bvp, 0); MMAQ_PQ(ACC, bvp, 1); PRIO0

__global__ __launch_bounds__(512) void gemm3_kernel(
    const unsigned short* __restrict__ xo,
    const unsigned short* __restrict__ xee,
    const unsigned short* __restrict__ xeo,
    const unsigned short* __restrict__ Bo,
    const unsigned short* __restrict__ Bp,
    const unsigned short* __restrict__ Bq,
    float* __restrict__ out) {
  __shared__ __align__(16) unsigned short lds[73728];   // 144 KiB

  const int bx = blockIdx.x;           // 256 identical blocks
  const int row0 = (bx & 15) * 256;
  const int c0 = (bx >> 4) * 32;       // quad-group base k'

  const int tid = threadIdx.x;
  const int lane = tid & 63;
  const int wave = tid >> 6;
  const int wm = wave >> 1;            // 0..3 : 64-row strip
  const int wn = wave & 1;             // 0..1 : col-half (strip pair)
  const int lr = lane & 15, kq = lane >> 4;
  const int st_r = tid >> 3;                         // staging row 0..63
  const int st_c = ((tid & 7) ^ (st_r & 7)) * 8;     // pre-swizzled src chunk
  const int cA0 = (kq ^ (lr & 7)) * 8;               // swizzled ds_read chunks
  const int cA1 = ((4 + kq) ^ (lr & 7)) * 8;

  // Per-thread B staging row pointers (strip-gather; mirrors reversed).
  const int ru0 = (st_r < 32) ? (c0 + st_r) : (2047 - c0 - (st_r - 32));
  const int ru1 = (st_r < 32) ? (1023 - c0 - st_r) : (1024 + c0 + (st_r - 32));
  const int rpq = (st_r < 32) ? (c0 + st_r) : (1023 - c0 - (st_r - 32));
  const unsigned short* sBo0 = Bo + (size_t)ru0 * 2048 + st_c;
  const unsigned short* sBo1 = Bo + (size_t)ru1 * 2048 + st_c;
  const unsigned short* sBp  = Bp + (size_t)rpq * 1024 + st_c;
  const unsigned short* sBq  = Bq + (size_t)rpq * 1024 + st_c;

  f32x4 uacc[4][4], pacc[4][2], qacc[4][2];
#pragma unroll
  for (int i = 0; i < 4; ++i) {
#pragma unroll
    for (int j = 0; j < 4; ++j) uacc[i][j] = (f32x4){0.f, 0.f, 0.f, 0.f};
#pragma unroll
    for (int j = 0; j < 2; ++j) {
      pacc[i][j] = (f32x4){0.f, 0.f, 0.f, 0.f};
      qacc[i][j] = (f32x4){0.f, 0.f, 0.f, 0.f};
    }
  }
  short8 av[4][2], bv0[2][2], bv1[2][2], bvp[2][2];

  // Prologue: stage U0 -> buf0, U1 -> buf1 (12 loads); drain U0, keep U1.
  STG_U(AB0, BB0, 0);
  STG_U(AB1, BB1, 64);
  W_VM6; PH_BAR;

  // ================= U segment: 32 K-tiles, tri-buffered ===================
  for (int it = 0; it < 10; ++it) {      // tiles 0..29
    const int kb = it * 192;
    U_CORE(AB0, BB0); STG_U(AB2, BB2, kb + 128); U_MMA; W_VM6; PH_BAR;
    U_CORE(AB1, BB1); STG_U(AB0, BB0, kb + 192); U_MMA; W_VM6; PH_BAR;
    U_CORE(AB2, BB2); STG_U(AB1, BB1, kb + 256); U_MMA; W_VM6; PH_BAR;
  }
  // U30 (buf0): stage P0 -> buf2 (drain U31's 6, leave P0's 5)
  U_CORE(AB0, BB0); STG_P(AB2, BB2, 0); U_MMA; W_VM5; PH_BAR;
  // U31 (buf1): stage P1 -> buf0 (drain P0's 5, leave P1's 5)
  U_CORE(AB1, BB1); STG_P(AB0, BB0, 64); U_MMA; W_VM5; PH_BAR;

  // ================= P segment: 16 K-tiles (P t in buf (t+2)%3) ============
  for (int it = 0; it < 4; ++it) {       // tiles 0..11
    const int kb = it * 192;
    PQ_CORE(AB2, BB2); STG_P(AB1, BB1, kb + 128); PQ_MMA(pacc); W_VM5; PH_BAR;
    PQ_CORE(AB0, BB0); STG_P(AB2, BB2, kb + 192); PQ_MMA(pacc); W_VM5; PH_BAR;
    PQ_CORE(AB1, BB1); STG_P(AB0, BB0, kb + 256); PQ_MMA(pacc); W_VM5; PH_BAR;
  }
  PQ_CORE(AB2, BB2); STG_P(AB1, BB1, 896); PQ_MMA(pacc); W_VM5; PH_BAR;  // P12
  PQ_CORE(AB0, BB0); STG_P(AB2, BB2, 960); PQ_MMA(pacc); W_VM5; PH_BAR;  // P13
  PQ_CORE(AB1, BB1); STG_Q(AB0, BB0, 0);   PQ_MMA(pacc); W_VM5; PH_BAR;  // P14
  PQ_CORE(AB2, BB2); STG_Q(AB1, BB1, 64);  PQ_MMA(pacc); W_VM5; PH_BAR;  // P15

  // ================= Q segment: 16 K-tiles (Q t in buf t%3) ================
  for (int it = 0; it < 4; ++it) {       // tiles 0..11
    const int kb = it * 192;
    PQ_CORE(AB0, BB0); STG_Q(AB2, BB2, kb + 128); PQ_MMA(qacc); W_VM5; PH_BAR;
    PQ_CORE(AB1, BB1); STG_Q(AB0, BB0, kb + 192); PQ_MMA(qacc); W_VM5; PH_BAR;
    PQ_CORE(AB2, BB2); STG_Q(AB1, BB1, kb + 256); PQ_MMA(qacc); W_VM5; PH_BAR;
  }
  PQ_CORE(AB0, BB0); STG_Q(AB2, BB2, 896); PQ_MMA(qacc); W_VM5; PH_BAR;  // Q12
  PQ_CORE(AB1, BB1); STG_Q(AB0, BB0, 960); PQ_MMA(qacc); W_VM5; PH_BAR;  // Q13
  PQ_CORE(AB2, BB2); PQ_MMA(qacc); W_VM0; PH_BAR;                        // Q14
  PQ_CORE(AB0, BB0); PQ_MMA(qacc);                                       // Q15

  // ===================== epilogue: full two-level fold =====================
  // wn=0: u1=u[k'], u4=u[2047-k'], p/q at k'.  wn=1: u1=u[1023-k'],
  // u4=u[1024+k'], p/q at 1023-k'.  k' = c0+cs, cs = j*16+lr.
#pragma unroll
  for (int i = 0; i < 4; ++i)
#pragma unroll
    for (int j = 0; j < 2; ++j)
#pragma unroll
      for (int rr = 0; rr < 4; ++rr) {
        const int r_out = row0 + wm * 64 + i * 16 + kq * 4 + rr;
        float* orow = out + (size_t)r_out * NN;
        const int cs = j * 16 + lr;
        const float u1 = uacc[i][j][rr];
        const float u4 = uacc[i][j + 2][rr];
        const float pa = pacc[i][j][rr];
        const float qa = qacc[i][j][rr];
        const float v1 = pa + qa;
        const float v2 = qa - pa;
        if (wn == 0) {
          orow[c0 + cs]        = v1 + u1;   // y[k']
          orow[4095 - c0 - cs] = u1 - v1;   // y[4095-k']
          orow[2047 - c0 - cs] = v2 + u4;   // y[2047-k']
          orow[2048 + c0 + cs] = u4 - v2;   // y[2048+k']
        } else {
          orow[1023 - c0 - cs] = v1 + u1;   // y[1023-k']
          orow[3072 + c0 + cs] = u1 - v1;   // y[3072+k']
          orow[1024 + c0 + cs] = v2 + u4;   // y[1024+k']
          orow[3071 - c0 - cs] = u4 - v2;   // y[3071-k']
        }
      }
}

extern "C" void kernel_launch(void* const* d_in, const int* in_sizes, int n_in,
                              void* d_out, int out_size, void* d_ws, size_t ws_size,
                              hipStream_t stream) {
  const float* x = (const float*)d_in[0];
  float* out = (float*)d_out;
  unsigned short* xo  = (unsigned short*)d_ws;            // 16 MB
  unsigned short* xee = xo + (size_t)NN * 2048;           // 8 MB
  unsigned short* xeo = xee + (size_t)NN * 1024;          // 8 MB
  unsigned short* Bo  = xeo + (size_t)NN * 1024;          // 8 MB
  unsigned short* Bp  = Bo + (size_t)2048 * 2048;         // 2 MB
  unsigned short* Bq  = Bp + (size_t)1024 * 1024;         // 2 MB -> 44 MB total

  int prep_threads = NXS + NBO + 2 * NBP;
  prep_kernel<<<prep_threads / 256, 256, 0, stream>>>(x, xo, xee, xeo, Bo, Bp, Bq);

  gemm3_kernel<<<256, 512, 0, stream>>>(xo, xee, xeo, Bo, Bp, Bq, out);
}